// Round 6
// baseline (245.343 us; speedup 1.0000x reference)
//
#include <hip/hip_runtime.h>
#include <stdint.h>

// VQ-VAE nearest-codeword quantization, MI355X (gfx950).
// M=16384 rows, D=256 dims, K=8192 codewords.
// argmin_k ||x-c_k||^2 == argmin_k ( ||c_k||^2 - 2 x.c_k )
//
// R6: no-barrier flat GEMM. Each wave owns 32 rows x one 512-col split:
//  - A fragments (8 KB/wave) hoisted into 32 VGPRs ONCE (R5 re-loaded 4x).
//  - 4 waves/block share the SAME split -> identical B addresses -> L1 hits
//    (L2 B-traffic ~256 MB ~ 8 us).
//  - software-pipelined inner loop: next group's B frags + c2 prefetched
//    before current group's 4 MFMA + epilogue (ws padded so last prefetch
//    can't fault).
//  - zero __shared__ / __syncthreads in vq_main; cross-fr bitonic merge
//    leaves lanes fr==0 holding exactly the wave's 32 rows -> direct store.
//  - __launch_bounds__(256,4): ~118 VGPR est -> 4 waves/SIMD, 8192 waves.
// prep also writes out_ze (reads x anyway) and bakes +1024 into c2 so merge
// skips the full x read and one output stream.
// R5 correctness kept verbatim: forced-RTNE fp8, TOP-4 per split kept set,
// EPS=20 fp64 rescore (ties -> smaller index, matching np.argmin).

#define M_ROWS 16384
#define D_DIM  256
#define K_CB   8192
#define NSPLIT 16           // 512 codewords per split
#define CW     512          // cols per split (per wave)
#define EPS 20.0f

typedef float f32x4 __attribute__((ext_vector_type(4)));
typedef int   int8v __attribute__((ext_vector_type(8)));

__device__ __forceinline__ uint32_t umin32(uint32_t a, uint32_t b) { return a < b ? a : b; }
__device__ __forceinline__ uint32_t umax32(uint32_t a, uint32_t b) { return a > b ? a : b; }

// round f32 to 3 mantissa bits, RTNE (carry into exponent handled by the add)
__device__ __forceinline__ float rtne3(float f) {
  uint32_t u = __float_as_uint(f);
  u = (u + 0x0007FFFFu + ((u >> 20) & 1u)) & 0xFFF00000u;
  return __uint_as_float(u);
}

__device__ __forceinline__ uint32_t fp8x4(const f32x4 v) {
  // pre-rounded values are exactly representable -> intrinsic is exact
  int p = __builtin_amdgcn_cvt_pk_fp8_f32(rtne3(v[0]), rtne3(v[1]), 0, false);
  p = __builtin_amdgcn_cvt_pk_fp8_f32(rtne3(v[2]), rtne3(v[3]), p, true);
  return (uint32_t)p;
}

// -- prep: x -> Ap fp8 + out_ze ; cb -> Bp fp8 + c2s = ||c||^2 + 1024 (fp64) --
__global__ __launch_bounds__(256) void prep(const float* __restrict__ x,
                                            const float* __restrict__ cb,
                                            uint8_t* __restrict__ Ap,
                                            uint8_t* __restrict__ Bp,
                                            float* __restrict__ c2s,
                                            float* __restrict__ out_ze) {
  const int w = threadIdx.x >> 6, lane = threadIdx.x & 63;
  if (blockIdx.x < M_ROWS / 4) {
    const int row = blockIdx.x * 4 + w;                 // one wave per x row
    const f32x4 v = *(const f32x4*)(x + (size_t)row * D_DIM + lane * 4);
    *(uint32_t*)(Ap + (size_t)row * D_DIM + lane * 4) = fp8x4(v);
    *(f32x4*)(out_ze + (size_t)row * D_DIM + lane * 4) = v;   // identity encoder
  } else {
    const int row = (blockIdx.x - M_ROWS / 4) * 4 + w;  // one wave per codeword
    const f32x4 v = *(const f32x4*)(cb + (size_t)row * D_DIM + lane * 4);
    *(uint32_t*)(Bp + (size_t)row * D_DIM + lane * 4) = fp8x4(v);
    double s = 0.0;
#pragma unroll
    for (int t = 0; t < 4; ++t) s += (double)v[t] * (double)v[t];
#pragma unroll
    for (int m = 1; m < 64; m <<= 1) s += __shfl_xor(s, m, 64);
    if (lane == 0) c2s[row] = (float)s + 1024.0f;       // pre-shifted: s>0 packing
  }
}

// ---- main: barrier-free fp8 K=256 flat GEMM + fused packed top-4 per split ----
__global__ __launch_bounds__(256, 4) void vq_main(const uint8_t* __restrict__ Ap,
                                                  const uint8_t* __restrict__ Bp,
                                                  const float* __restrict__ c2s,
                                                  uint4* __restrict__ part) {
  const int w    = threadIdx.x >> 6;
  const int lane = threadIdx.x & 63;
  const int fr   = lane & 15;         // frag m/n index
  const int fq   = lane >> 4;         // frag k-quarter (32 contiguous bytes)

  const int rowBase = blockIdx.x * 128 + w * 32;        // wave owns 32 rows
  const int colBase = blockIdx.y * CW;                  // ... x one 512-col split

  // hoisted A fragments: rows rowBase + i*16 + fr, bytes fq*32 + kh*128
  int8v af[2][2];
  {
    const uint8_t* ab = Ap + (size_t)(rowBase + fr) * D_DIM + fq * 32;
#pragma unroll
    for (int i = 0; i < 2; ++i)
#pragma unroll
      for (int kh = 0; kh < 2; ++kh)
        af[i][kh] = *(const int8v*)(ab + (size_t)(i * 16) * D_DIM + kh * 128);
  }

  // sorted top-4 per slot [i][r], packed ((s+1024) bits & ~511) | col9
  uint32_t t1[2][4], t2[2][4], t3[2][4], t4[2][4];
#pragma unroll
  for (int i = 0; i < 2; ++i)
#pragma unroll
    for (int r = 0; r < 4; ++r) {
      t1[i][r] = 0x7f7ffe00u; t2[i][r] = 0x7f7ffe00u;
      t3[i][r] = 0x7f7ffe00u; t4[i][r] = 0x7f7ffe00u;
    }

  const uint8_t* bptr = Bp + (size_t)(colBase + fr) * D_DIM + fq * 32;
  const float*   cptr = c2s + colBase + fr;

  int8v bf0 = *(const int8v*)(bptr);        // prime the pipeline
  int8v bf1 = *(const int8v*)(bptr + 128);
  float cv  = *cptr;
  int col9  = fr;

  for (int g = 0; g < CW / 16; ++g) {       // 32 groups of 16 cols
    bptr += 16 * D_DIM;                     // prefetch next group (ws padded:
    cptr += 16;                             //  last iter reads 4 KB slack)
    const int8v nb0 = *(const int8v*)(bptr);
    const int8v nb1 = *(const int8v*)(bptr + 128);
    const float ncv = *cptr;

    f32x4 acc[2];
#pragma unroll
    for (int i = 0; i < 2; ++i) {
      acc[i] = (f32x4){0.f, 0.f, 0.f, 0.f};
      acc[i] = __builtin_amdgcn_mfma_scale_f32_16x16x128_f8f6f4(
          af[i][0], bf0, acc[i], 0, 0, 0, 0x7f7f7f7f, 0, 0x7f7f7f7f);
      acc[i] = __builtin_amdgcn_mfma_scale_f32_16x16x128_f8f6f4(
          af[i][1], bf1, acc[i], 0, 0, 0, 0x7f7f7f7f, 0, 0x7f7f7f7f);
    }

    // epilogue: s = (1024+c2) - 2*cross; pack; sorted top-4 insert (7 int ops)
#pragma unroll
    for (int i = 0; i < 2; ++i)
#pragma unroll
      for (int r = 0; r < 4; ++r) {
        const float s = fmaf(-2.0f, acc[i][r], cv);
        const uint32_t p = (__float_as_uint(s) & ~511u) | (uint32_t)col9;
        const uint32_t b = umax32(t1[i][r], p); t1[i][r] = umin32(t1[i][r], p);
        const uint32_t d = umax32(t2[i][r], b); t2[i][r] = umin32(t2[i][r], b);
        const uint32_t f = umax32(t3[i][r], d); t3[i][r] = umin32(t3[i][r], d);
        t4[i][r] = umin32(t4[i][r], f);
      }

    bf0 = nb0; bf1 = nb1; cv = ncv; col9 += 16;
  }

  // cross-fr bitonic merge (lanes with same fq = same rows); then lane fr==0
  // of each fq holds top-4 of all 512 cols for row i*16 + fq*4 + r.
#pragma unroll
  for (int i = 0; i < 2; ++i)
#pragma unroll
    for (int r = 0; r < 4; ++r) {
      uint32_t a1 = t1[i][r], a2 = t2[i][r], a3 = t3[i][r], a4 = t4[i][r];
#pragma unroll
      for (int m = 1; m < 16; m <<= 1) {
        const uint32_t b1 = __shfl_xor(a1, m, 64);
        const uint32_t b2 = __shfl_xor(a2, m, 64);
        const uint32_t b3 = __shfl_xor(a3, m, 64);
        const uint32_t b4 = __shfl_xor(a4, m, 64);
        uint32_t c1 = umin32(a1, b4), c2_ = umin32(a2, b3);
        uint32_t c3 = umin32(a3, b2), c4 = umin32(a4, b1);
        uint32_t lo, hi;
        lo = umin32(c1, c3); hi = umax32(c1, c3); c1 = lo; c3 = hi;
        lo = umin32(c2_, c4); hi = umax32(c2_, c4); c2_ = lo; c4 = hi;
        lo = umin32(c1, c2_); hi = umax32(c1, c2_); c1 = lo; c2_ = hi;
        lo = umin32(c3, c4); hi = umax32(c3, c4); c3 = lo; c4 = hi;
        a1 = c1; a2 = c2_; a3 = c3; a4 = c4;
      }
      if (fr == 0) {
        const int row = rowBase + i * 16 + fq * 4 + r;   // C/D layout (m89)
        part[(size_t)row * NSPLIT + blockIdx.y] = make_uint4(a1, a2, a3, a4);
      }
    }
}

// -------- merge: 64 candidates/row -> certain winner or fp64 rescore --------
__global__ __launch_bounds__(256) void vq_merge(const uint32_t* __restrict__ part,
                                                const float* __restrict__ x,
                                                const float* __restrict__ cb,
                                                float* __restrict__ out) {
  const int w = threadIdx.x >> 6, lane = threadIdx.x & 63;
  const int row = blockIdx.x * 4 + w;                 // one wave per row

  const uint32_t pk = part[(size_t)row * 64 + lane];  // coalesced, 1 cand/lane
  const int gidx = (lane >> 2) * (K_CB / NSPLIT) + (int)(pk & 511u);

  // integer min == numeric min (all packed values positive)
  uint32_t pmin = pk;
#pragma unroll
  for (int m = 1; m < 64; m <<= 1) {
    const uint32_t o = __shfl_xor(pmin, m, 64);
    pmin = pmin < o ? pmin : o;
  }
  const float vmin = __uint_as_float(pmin & ~511u);
  const float vme  = __uint_as_float(pk & ~511u);
  const unsigned long long mask = __ballot(vme <= vmin + EPS);

  int winner;
  if (__popcll(mask) == 1) {
    winner = __shfl(gidx, __ffsll((long long)mask) - 1, 64);
  } else {
    // exact fp64 rescore of the qualifiers (ties -> smaller index, like np)
    const f32x4 xv = *(const f32x4*)(x + (size_t)row * D_DIM + lane * 4);
    double bestd = 1.0e300;
    int bidx = 0x7fffffff;
    unsigned long long mm = mask;
    while (mm) {
      const int q = __ffsll((long long)mm) - 1;
      mm &= mm - 1;
      const int ci = __shfl(gidx, q, 64);
      const f32x4 cv = *(const f32x4*)(cb + (size_t)ci * D_DIM + lane * 4);
      double s = 0.0;
#pragma unroll
      for (int t = 0; t < 4; ++t) {
        const double dx = (double)xv[t] - (double)cv[t];
        s += dx * dx;
      }
#pragma unroll
      for (int m = 1; m < 64; m <<= 1) s += __shfl_xor(s, m, 64);
      if (s < bestd || (s == bestd && ci < bidx)) { bestd = s; bidx = ci; }
    }
    winner = bidx;
  }

  float* out_recon = out;                               // out_ze written by prep
  float* out_zq    = out + 2 * (size_t)M_ROWS * D_DIM;
  float* out_idx   = out + 3 * (size_t)M_ROWS * D_DIM;

  const f32x4 cv = *(const f32x4*)(cb + (size_t)winner * D_DIM + lane * 4);
  *(f32x4*)(out_recon + (size_t)row * D_DIM + lane * 4) = cv;  // identity decoder
  *(f32x4*)(out_zq    + (size_t)row * D_DIM + lane * 4) = cv;
  if (lane == 0) out_idx[row] = (float)winner;
}

extern "C" void kernel_launch(void* const* d_in, const int* in_sizes, int n_in,
                              void* d_out, int out_size, void* d_ws, size_t ws_size,
                              hipStream_t stream) {
  const float* x  = (const float*)d_in[0];
  const float* cb = (const float*)d_in[1];
  float* out = (float*)d_out;

  // ws: c2s 32 KB | part uint4[16384][16] 4 MB | Ap fp8 4 MB | Bp fp8 2 MB | 4 KB pad
  char* ws = (char*)d_ws;
  float*    c2s  = (float*)ws;
  uint4*    part = (uint4*)(ws + 32768);
  uint8_t*  Ap   = (uint8_t*)(ws + 32768 + 4194304);
  uint8_t*  Bp   = Ap + (size_t)M_ROWS * D_DIM;
  if (ws_size < (size_t)(32768 + 4194304 + 4194304 + 2097152 + 4096)) return;

  float* out_ze = out + (size_t)M_ROWS * D_DIM;

  prep    <<<dim3(M_ROWS / 4 + K_CB / 4), dim3(256), 0, stream>>>(x, cb, Ap, Bp, c2s, out_ze);
  vq_main <<<dim3(M_ROWS / 128, NSPLIT), dim3(256), 0, stream>>>(Ap, Bp, c2s, part);
  vq_merge<<<dim3(M_ROWS / 4), dim3(256), 0, stream>>>((const uint32_t*)part, x, cb, out);
}

// Round 7
// 186.302 us; speedup vs baseline: 1.3169x; 1.3169x over previous
//
#include <hip/hip_runtime.h>
#include <stdint.h>

// VQ-VAE nearest-codeword quantization, MI355X (gfx950).
// M=16384 rows, D=256 dims, K=8192 codewords.
// argmin_k ||x-c_k||^2 == argmin_k ( ||c_k||^2 - 2 x.c_k )
//
// R7: back to the DMA/LDS structure (R4: 97.7 us) after R6's register-stream
// experiment regressed (146 us: compiler defeated the prefetch; VGPR=48 showed
// my register plan never materialized). Fixes over R4:
//  - DMA[c+1] issued RIGHT AFTER the stage barrier, BEFORE computing stage c:
//    ~600+ cycles of issue distance, so the next barrier's structural
//    vmcnt(0) drain finds the DMA complete (R4 issued at zero distance).
//  - A fragments in VGPRs for the whole kernel (R4 re-DMA'd A 4x per block).
//  - 16-chunk XOR swizzle for 256 B rows: phys chunk = logical ^ (row & 15);
//    b128 reads land exactly 8 lanes per 4-bank group (optimal).
//  - one barrier per 64-col stage, 8 stages; no LDS reduction (direct store).
// Correctness (proven absmax 0.0 in R5/R6): forced-RTNE fp8, TOP-4 per
// 512-col split, EPS=20 fp64 rescore, ties -> smaller index like np.argmin.

#define M_ROWS 16384
#define D_DIM  256
#define K_CB   8192
#define NSPLIT 16           // 512 codewords per split
#define CHUNK  64           // cols staged per barrier
#define EPS 20.0f

typedef float f32x4 __attribute__((ext_vector_type(4)));
typedef int   int4v __attribute__((ext_vector_type(4)));
typedef int   int8v __attribute__((ext_vector_type(8)));

__device__ __forceinline__ uint32_t umin32(uint32_t a, uint32_t b) { return a < b ? a : b; }
__device__ __forceinline__ uint32_t umax32(uint32_t a, uint32_t b) { return a > b ? a : b; }

__device__ __forceinline__ void gld_lds16(const void* g, void* l) {
  // async global->LDS, 16B/lane; LDS dest is wave-uniform base + lane*16.
  __builtin_amdgcn_global_load_lds((__attribute__((address_space(1))) void*)g,
                                   (__attribute__((address_space(3))) void*)l,
                                   16, 0, 0);
}

// round f32 to 3 mantissa bits, RTNE (carry into exponent handled by the add)
__device__ __forceinline__ float rtne3(float f) {
  uint32_t u = __float_as_uint(f);
  u = (u + 0x0007FFFFu + ((u >> 20) & 1u)) & 0xFFF00000u;
  return __uint_as_float(u);
}

__device__ __forceinline__ uint32_t fp8x4(const f32x4 v) {
  // pre-rounded values are exactly representable -> intrinsic is exact
  int p = __builtin_amdgcn_cvt_pk_fp8_f32(rtne3(v[0]), rtne3(v[1]), 0, false);
  p = __builtin_amdgcn_cvt_pk_fp8_f32(rtne3(v[2]), rtne3(v[3]), p, true);
  return (uint32_t)p;
}

// -- prep: x -> Ap fp8 + out_ze ; cb -> Bp fp8 + c2s = ||c||^2 + 1024 (fp64) --
__global__ __launch_bounds__(256) void prep(const float* __restrict__ x,
                                            const float* __restrict__ cb,
                                            uint8_t* __restrict__ Ap,
                                            uint8_t* __restrict__ Bp,
                                            float* __restrict__ c2s,
                                            float* __restrict__ out_ze) {
  const int w = threadIdx.x >> 6, lane = threadIdx.x & 63;
  if (blockIdx.x < M_ROWS / 4) {
    const int row = blockIdx.x * 4 + w;                 // one wave per x row
    const f32x4 v = *(const f32x4*)(x + (size_t)row * D_DIM + lane * 4);
    *(uint32_t*)(Ap + (size_t)row * D_DIM + lane * 4) = fp8x4(v);
    *(f32x4*)(out_ze + (size_t)row * D_DIM + lane * 4) = v;   // identity encoder
  } else {
    const int row = (blockIdx.x - M_ROWS / 4) * 4 + w;  // one wave per codeword
    const f32x4 v = *(const f32x4*)(cb + (size_t)row * D_DIM + lane * 4);
    *(uint32_t*)(Bp + (size_t)row * D_DIM + lane * 4) = fp8x4(v);
    double s = 0.0;
#pragma unroll
    for (int t = 0; t < 4; ++t) s += (double)v[t] * (double)v[t];
#pragma unroll
    for (int m = 1; m < 64; m <<= 1) s += __shfl_xor(s, m, 64);
    if (lane == 0) c2s[row] = (float)s + 1024.0f;       // pre-shifted: s>0 packing
  }
}

// ---- main: fp8 K=256 GEMM, DMA-pipelined LDS B, fused packed top-4/split ----
__global__ __launch_bounds__(256, 3) void vq_main(const uint8_t* __restrict__ Ap,
                                                  const uint8_t* __restrict__ Bp,
                                                  const float* __restrict__ c2s,
                                                  uint4* __restrict__ part) {
  __shared__ uint8_t Bs[2][CHUNK * D_DIM];   // 2 x 16 KB, chunk-swizzled

  const int w    = threadIdx.x >> 6;
  const int lane = threadIdx.x & 63;
  const int fr   = lane & 15;         // frag m/n index
  const int fq   = lane >> 4;         // frag k-quarter (32 contiguous bytes)

  const int rowBase = blockIdx.x * 128 + w * 32;        // wave owns 32 rows
  const int colBase = blockIdx.y * 512;                 // block owns one split

  // A fragments for the whole kernel: rows rowBase + i*16 + fr, k = fq*32 + kh*128
  int8v af[2][2];
  {
    const uint8_t* ab = Ap + (size_t)(rowBase + fr) * D_DIM + fq * 32;
#pragma unroll
    for (int i = 0; i < 2; ++i)
#pragma unroll
      for (int kh = 0; kh < 2; ++kh)
        af[i][kh] = *(const int8v*)(ab + (size_t)(i * 16) * D_DIM + kh * 128);
  }

  // sorted top-4 per slot [i][r], packed ((s+1024) bits & ~511) | col9
  uint32_t t1[2][4], t2[2][4], t3[2][4], t4[2][4];
#pragma unroll
  for (int i = 0; i < 2; ++i)
#pragma unroll
    for (int r = 0; r < 4; ++r) {
      t1[i][r] = 0x7f7ffe00u; t2[i][r] = 0x7f7ffe00u;
      t3[i][r] = 0x7f7ffe00u; t4[i][r] = 0x7f7ffe00u;
    }

  // DMA one 64-row chunk of B' into Bs[buf]; wave w stages rows [w*16, w*16+16).
  // Phys 16B chunk p of row n holds logical chunk p^(n&15); gld dest is
  // base+lane*16, so the swizzle is applied on the GLOBAL source (R1-proven).
  const int dRow = lane >> 4;                           // 0..3 within 4-row group
  const int dChk = lane & 15;                           // phys chunk slot
#define STAGE_DMA(c, buf)                                                        \
  {                                                                              \
    _Pragma("unroll")                                                            \
    for (int ii = 0; ii < 4; ++ii) {                                             \
      const int r0  = w * 16 + ii * 4;                                           \
      const int row = r0 + dRow;                                                 \
      gld_lds16(Bp + (size_t)(colBase + (c) * CHUNK + row) * D_DIM +             \
                    ((dChk ^ (row & 15)) << 4),                                  \
                &Bs[buf][r0 * D_DIM] + lane * 16);                               \
    }                                                                            \
  }

  STAGE_DMA(0, 0);

  for (int c = 0; c < 512 / CHUNK; ++c) {               // 8 stages
    __syncthreads();              // DMA[c] landed (issued a full stage ago)
    if (c < 512 / CHUNK - 1) STAGE_DMA(c + 1, (c + 1) & 1);

    const uint8_t* bsb = Bs[c & 1];
    const int cb0 = c * CHUNK;
    float cvv[4];
#pragma unroll
    for (int jj = 0; jj < 4; ++jj)                      // hoist c2 loads
      cvv[jj] = c2s[colBase + cb0 + jj * 16 + fr];

#pragma unroll
    for (int jj = 0; jj < 4; ++jj) {                    // 4 col-frags of 16
      const uint8_t* bp = bsb + (jj * 16 + fr) * D_DIM;
      f32x4 acc[2];
      acc[0] = (f32x4){0.f, 0.f, 0.f, 0.f};
      acc[1] = (f32x4){0.f, 0.f, 0.f, 0.f};
#pragma unroll
      for (int kh = 0; kh < 2; ++kh) {
        const int L0 = kh * 8 + fq * 2;                 // logical 16B chunk
        const int4v lo = *(const int4v*)(bp + ((L0 ^ fr) << 4));
        const int4v hi = *(const int4v*)(bp + (((L0 + 1) ^ fr) << 4));
        int8v bf;
#pragma unroll
        for (int t = 0; t < 4; ++t) { bf[t] = lo[t]; bf[4 + t] = hi[t]; }
#pragma unroll
        for (int i = 0; i < 2; ++i)
          acc[i] = __builtin_amdgcn_mfma_scale_f32_16x16x128_f8f6f4(
              af[i][kh], bf, acc[i], 0, 0,       // cbsz=fp8, blgp=fp8
              0, 0x7f7f7f7f, 0, 0x7f7f7f7f);     // unit E8M0 scales
      }
      // epilogue: s = (1024+c2) - 2*cross; pack; sorted top-4 insert
      const int col9 = cb0 + jj * 16 + fr;
      const float cv = cvv[jj];
#pragma unroll
      for (int i = 0; i < 2; ++i)
#pragma unroll
        for (int r = 0; r < 4; ++r) {
          const float s = fmaf(-2.0f, acc[i][r], cv);
          const uint32_t p = (__float_as_uint(s) & ~511u) | (uint32_t)col9;
          const uint32_t b = umax32(t1[i][r], p); t1[i][r] = umin32(t1[i][r], p);
          const uint32_t d = umax32(t2[i][r], b); t2[i][r] = umin32(t2[i][r], b);
          const uint32_t f = umax32(t3[i][r], d); t3[i][r] = umin32(t3[i][r], d);
          t4[i][r] = umin32(t4[i][r], f);
        }
    }
  }

  // cross-fr bitonic merge (lanes with same fq hold the same rows, disjoint
  // cols); lane fr==0 of each fq then stores its rows' top-4 directly.
#pragma unroll
  for (int i = 0; i < 2; ++i)
#pragma unroll
    for (int r = 0; r < 4; ++r) {
      uint32_t a1 = t1[i][r], a2 = t2[i][r], a3 = t3[i][r], a4 = t4[i][r];
#pragma unroll
      for (int m = 1; m < 16; m <<= 1) {
        const uint32_t b1 = __shfl_xor(a1, m, 64);
        const uint32_t b2 = __shfl_xor(a2, m, 64);
        const uint32_t b3 = __shfl_xor(a3, m, 64);
        const uint32_t b4 = __shfl_xor(a4, m, 64);
        uint32_t c1 = umin32(a1, b4), c2_ = umin32(a2, b3);
        uint32_t c3 = umin32(a3, b2), c4 = umin32(a4, b1);
        uint32_t lo, hi;
        lo = umin32(c1, c3); hi = umax32(c1, c3); c1 = lo; c3 = hi;
        lo = umin32(c2_, c4); hi = umax32(c2_, c4); c2_ = lo; c4 = hi;
        lo = umin32(c1, c2_); hi = umax32(c1, c2_); c1 = lo; c2_ = hi;
        lo = umin32(c3, c4); hi = umax32(c3, c4); c3 = lo; c4 = hi;
        a1 = c1; a2 = c2_; a3 = c3; a4 = c4;
      }
      if (fr == 0) {
        const int row = rowBase + i * 16 + fq * 4 + r;   // C/D layout (m89)
        part[(size_t)row * NSPLIT + blockIdx.y] = make_uint4(a1, a2, a3, a4);
      }
    }
}

// -------- merge: 64 candidates/row -> certain winner or fp64 rescore --------
__global__ __launch_bounds__(256) void vq_merge(const uint32_t* __restrict__ part,
                                                const float* __restrict__ x,
                                                const float* __restrict__ cb,
                                                float* __restrict__ out) {
  const int w = threadIdx.x >> 6, lane = threadIdx.x & 63;
  const int row = blockIdx.x * 4 + w;                 // one wave per row

  const uint32_t pk = part[(size_t)row * 64 + lane];  // coalesced, 1 cand/lane
  const int gidx = (lane >> 2) * (K_CB / NSPLIT) + (int)(pk & 511u);

  // integer min == numeric min (all packed values positive)
  uint32_t pmin = pk;
#pragma unroll
  for (int m = 1; m < 64; m <<= 1) {
    const uint32_t o = __shfl_xor(pmin, m, 64);
    pmin = pmin < o ? pmin : o;
  }
  const float vmin = __uint_as_float(pmin & ~511u);
  const float vme  = __uint_as_float(pk & ~511u);
  const unsigned long long mask = __ballot(vme <= vmin + EPS);

  int winner;
  if (__popcll(mask) == 1) {
    winner = __shfl(gidx, __ffsll((long long)mask) - 1, 64);
  } else {
    // exact fp64 rescore of the qualifiers (ties -> smaller index, like np)
    const f32x4 xv = *(const f32x4*)(x + (size_t)row * D_DIM + lane * 4);
    double bestd = 1.0e300;
    int bidx = 0x7fffffff;
    unsigned long long mm = mask;
    while (mm) {
      const int q = __ffsll((long long)mm) - 1;
      mm &= mm - 1;
      const int ci = __shfl(gidx, q, 64);
      const f32x4 cv = *(const f32x4*)(cb + (size_t)ci * D_DIM + lane * 4);
      double s = 0.0;
#pragma unroll
      for (int t = 0; t < 4; ++t) {
        const double dx = (double)xv[t] - (double)cv[t];
        s += dx * dx;
      }
#pragma unroll
      for (int m = 1; m < 64; m <<= 1) s += __shfl_xor(s, m, 64);
      if (s < bestd || (s == bestd && ci < bidx)) { bestd = s; bidx = ci; }
    }
    winner = bidx;
  }

  float* out_recon = out;                               // out_ze written by prep
  float* out_zq    = out + 2 * (size_t)M_ROWS * D_DIM;
  float* out_idx   = out + 3 * (size_t)M_ROWS * D_DIM;

  const f32x4 cv = *(const f32x4*)(cb + (size_t)winner * D_DIM + lane * 4);
  *(f32x4*)(out_recon + (size_t)row * D_DIM + lane * 4) = cv;  // identity decoder
  *(f32x4*)(out_zq    + (size_t)row * D_DIM + lane * 4) = cv;
  if (lane == 0) out_idx[row] = (float)winner;
}

extern "C" void kernel_launch(void* const* d_in, const int* in_sizes, int n_in,
                              void* d_out, int out_size, void* d_ws, size_t ws_size,
                              hipStream_t stream) {
  const float* x  = (const float*)d_in[0];
  const float* cb = (const float*)d_in[1];
  float* out = (float*)d_out;

  // ws: c2s 32 KB | part uint4[16384][16] 4 MB | Ap fp8 4 MB | Bp fp8 2 MB | pad
  char* ws = (char*)d_ws;
  float*    c2s  = (float*)ws;
  uint4*    part = (uint4*)(ws + 32768);
  uint8_t*  Ap   = (uint8_t*)(ws + 32768 + 4194304);
  uint8_t*  Bp   = Ap + (size_t)M_ROWS * D_DIM;
  if (ws_size < (size_t)(32768 + 4194304 + 4194304 + 2097152 + 4096)) return;

  float* out_ze = out + (size_t)M_ROWS * D_DIM;

  prep    <<<dim3(M_ROWS / 4 + K_CB / 4), dim3(256), 0, stream>>>(x, cb, Ap, Bp, c2s, out_ze);
  vq_main <<<dim3(M_ROWS / 128, NSPLIT), dim3(256), 0, stream>>>(Ap, Bp, c2s, part);
  vq_merge<<<dim3(M_ROWS / 4), dim3(256), 0, stream>>>((const uint32_t*)part, x, cb, out);
}